// Round 7
// baseline (346.030 us; speedup 1.0000x reference)
//
#include <hip/hip_runtime.h>

#define NN 50000
#define NE 800000
#define NG 128
#define DIM 128
#define CO 10
#define CAP 64    // ELL row capacity; Poisson(16) tail beyond 64 is ~1e-20
#define NB 512    // pool stage-1 blocks

typedef unsigned long long ull;
typedef unsigned short ushort;

static __device__ __forceinline__ ushort f2bf(float f) {
    unsigned int u = __float_as_uint(f);
    unsigned int r = (u + 0x7FFF + ((u >> 16) & 1)) >> 16;   // RNE
    return (ushort)r;
}

// ---------------- ELL build: one pass, one atomic + one 8B store per edge ----------------
__global__ void k_ell(const int* __restrict__ src, const int* __restrict__ dst,
                      const float* __restrict__ ew, int* __restrict__ cnt,
                      ull* __restrict__ ell) {
    int e = blockIdx.x * blockDim.x + threadIdx.x;
    if (e >= NE) return;
    int d = dst[e], s = src[e];
    int slot = atomicAdd(&cnt[d], 1);
    if (slot < CAP) {
        ull rec = ((ull)__float_as_uint(ew[e]) << 32) | (unsigned int)s;
        ell[(size_t)d * CAP + slot] = rec;
    }
}

// ---------------- degree: wave per node, dinv = rsqrt(1 + sum ew) ----------------
__global__ __launch_bounds__(256) void k_deg(const int* __restrict__ cnt,
                                             const ull* __restrict__ ell,
                                             float* __restrict__ dinv) {
    int node = blockIdx.x * 4 + (threadIdx.x >> 6);
    int lane = threadIdx.x & 63;
    if (node >= NN) return;
    int n = cnt[node];
    float w = 0.0f;
    if (lane < n) w = __uint_as_float((unsigned int)(ell[(size_t)node * CAP + lane] >> 32));
#pragma unroll
    for (int off = 32; off; off >>= 1) w += __shfl_down(w, off);
    if (lane == 0) dinv[node] = rsqrtf(1.0f + w);
}

// ---------------- scale ew -> dinv[d]*ew*dinv[s], rewrite rec in place ----------------
__global__ __launch_bounds__(256) void k_scale(const int* __restrict__ cnt,
                                               ull* __restrict__ ell,
                                               const float* __restrict__ dinv) {
    int node = blockIdx.x * 4 + (threadIdx.x >> 6);
    int lane = threadIdx.x & 63;
    if (node >= NN) return;
    int n = cnt[node];
    if (lane >= n) return;
    size_t idx = (size_t)node * CAP + lane;
    ull rec = ell[idx];
    int s = (int)(unsigned int)(rec & 0xffffffffu);
    float ew = __uint_as_float((unsigned int)(rec >> 32));
    float v = dinv[node] * ew * dinv[s];
    ell[idx] = ((ull)__float_as_uint(v) << 32) | (unsigned int)s;
}

// ------- GEMM: C[M x 128](bf16) = A[M x 128](fp32) @ W[128 x 128](fp32) -------
__global__ __launch_bounds__(256) void k_gemm128(const float* __restrict__ A,
                                                 const float* __restrict__ W,
                                                 ushort* __restrict__ C, int M) {
    __shared__ float As[64][33];
    __shared__ float Bs[32][132];
    int tid = threadIdx.x;
    int block_row = blockIdx.x * 64;
    int tx = tid & 15;
    int ty = tid >> 4;
    int r0 = ty * 4;
    int c1 = tx * 4, c2 = 64 + tx * 4;
    float acc[4][8];
#pragma unroll
    for (int i = 0; i < 4; i++)
#pragma unroll
        for (int j = 0; j < 8; j++) acc[i][j] = 0.0f;

    for (int k0 = 0; k0 < 128; k0 += 32) {
#pragma unroll
        for (int l = 0; l < 2; l++) {
            int idx = tid + l * 256;
            int ar = idx >> 3;
            int ac = (idx & 7) * 4;
            int grow = block_row + ar;
            if (grow >= M) grow = M - 1;
            float4 v = *(const float4*)&A[(size_t)grow * 128 + k0 + ac];
            As[ar][ac + 0] = v.x; As[ar][ac + 1] = v.y;
            As[ar][ac + 2] = v.z; As[ar][ac + 3] = v.w;
        }
#pragma unroll
        for (int l = 0; l < 4; l++) {
            int idx = tid + l * 256;
            int br = idx >> 5;
            int bc = (idx & 31) * 4;
            float4 v = *(const float4*)&W[(size_t)(k0 + br) * 128 + bc];
            *(float4*)&Bs[br][bc] = v;
        }
        __syncthreads();
#pragma unroll
        for (int kk = 0; kk < 32; kk++) {
            float a0 = As[r0 + 0][kk];
            float a1 = As[r0 + 1][kk];
            float a2 = As[r0 + 2][kk];
            float a3 = As[r0 + 3][kk];
            float4 bl = *(float4*)&Bs[kk][c1];
            float4 bh = *(float4*)&Bs[kk][c2];
            acc[0][0] += a0 * bl.x; acc[0][1] += a0 * bl.y; acc[0][2] += a0 * bl.z; acc[0][3] += a0 * bl.w;
            acc[0][4] += a0 * bh.x; acc[0][5] += a0 * bh.y; acc[0][6] += a0 * bh.z; acc[0][7] += a0 * bh.w;
            acc[1][0] += a1 * bl.x; acc[1][1] += a1 * bl.y; acc[1][2] += a1 * bl.z; acc[1][3] += a1 * bl.w;
            acc[1][4] += a1 * bh.x; acc[1][5] += a1 * bh.y; acc[1][6] += a1 * bh.z; acc[1][7] += a1 * bh.w;
            acc[2][0] += a2 * bl.x; acc[2][1] += a2 * bl.y; acc[2][2] += a2 * bl.z; acc[2][3] += a2 * bl.w;
            acc[2][4] += a2 * bh.x; acc[2][5] += a2 * bh.y; acc[2][6] += a2 * bh.z; acc[2][7] += a2 * bh.w;
            acc[3][0] += a3 * bl.x; acc[3][1] += a3 * bl.y; acc[3][2] += a3 * bl.z; acc[3][3] += a3 * bl.w;
            acc[3][4] += a3 * bh.x; acc[3][5] += a3 * bh.y; acc[3][6] += a3 * bh.z; acc[3][7] += a3 * bh.w;
        }
        __syncthreads();
    }
#pragma unroll
    for (int i = 0; i < 4; i++) {
        int grow = block_row + r0 + i;
        if (grow < M) {
            ushort4 u1, u2;
            u1.x = f2bf(acc[i][0]); u1.y = f2bf(acc[i][1]); u1.z = f2bf(acc[i][2]); u1.w = f2bf(acc[i][3]);
            u2.x = f2bf(acc[i][4]); u2.y = f2bf(acc[i][5]); u2.z = f2bf(acc[i][6]); u2.w = f2bf(acc[i][7]);
            *(ushort4*)&C[(size_t)grow * 128 + c1] = u1;
            *(ushort4*)&C[(size_t)grow * 128 + c2] = u2;
        }
    }
}

// ---------------- GEMM3: z[M x 10](fp32) = A[M x 128](fp32) @ W3[128 x 10] ----------------
__global__ __launch_bounds__(256) void k_gemm10(const float* __restrict__ A,
                                                const float* __restrict__ W3,
                                                float* __restrict__ C3, int M) {
    __shared__ float Ws[1280];
    int tid = threadIdx.x;
    for (int i = tid; i < 1280; i += 256) Ws[i] = W3[i];
    __syncthreads();
    int col = tid & 15;
    int rloc = tid >> 4;
    int row = blockIdx.x * 16 + rloc;
    if (row >= M || col >= 10) return;
    const float* a = &A[(size_t)row * 128];
    float acc = 0.0f;
#pragma unroll
    for (int k = 0; k < 128; k += 4) {
        float4 av = *(const float4*)&a[k];
        acc += av.x * Ws[(k + 0) * 10 + col];
        acc += av.y * Ws[(k + 1) * 10 + col];
        acc += av.z * Ws[(k + 2) * 10 + col];
        acc += av.w * Ws[(k + 3) * 10 + col];
    }
    C3[(size_t)row * 10 + col] = acc;
}

// ---- ELL gather: one wave/node, bf16 h, packed rec + shfl broadcast, fp32 accum ----
__global__ __launch_bounds__(256) void k_gather128(const int* __restrict__ cnt,
                                                   const ull* __restrict__ ell,
                                                   const float* __restrict__ dinv,
                                                   const ushort* __restrict__ h,
                                                   const float* __restrict__ b,
                                                   float* __restrict__ outp,
                                                   int do_relu) {
    int node = blockIdx.x * 4 + (threadIdx.x >> 6);
    int lane = threadIdx.x & 63;
    if (node >= NN) return;
    int n = cnt[node];
    float di = dinv[node];
    unsigned int hp = *(const unsigned int*)&h[(size_t)node * 128 + lane * 2];
    float ax = di * di * __uint_as_float(hp << 16);
    float ay = di * di * __uint_as_float(hp & 0xffff0000u);
    ull rec = ell[(size_t)node * CAP + lane];
    int ce = (int)(unsigned int)(rec & 0xffffffffu);
    float we = __uint_as_float((unsigned int)(rec >> 32));
    int j = 0;
    for (; j + 3 < n; j += 4) {
        int s0 = __shfl(ce, j + 0), s1 = __shfl(ce, j + 1);
        int s2 = __shfl(ce, j + 2), s3 = __shfl(ce, j + 3);
        float w0 = __shfl(we, j + 0), w1 = __shfl(we, j + 1);
        float w2 = __shfl(we, j + 2), w3 = __shfl(we, j + 3);
        unsigned int p0 = *(const unsigned int*)&h[(size_t)s0 * 128 + lane * 2];
        unsigned int p1 = *(const unsigned int*)&h[(size_t)s1 * 128 + lane * 2];
        unsigned int p2 = *(const unsigned int*)&h[(size_t)s2 * 128 + lane * 2];
        unsigned int p3 = *(const unsigned int*)&h[(size_t)s3 * 128 + lane * 2];
        ax += w0 * __uint_as_float(p0 << 16) + w1 * __uint_as_float(p1 << 16)
            + w2 * __uint_as_float(p2 << 16) + w3 * __uint_as_float(p3 << 16);
        ay += w0 * __uint_as_float(p0 & 0xffff0000u) + w1 * __uint_as_float(p1 & 0xffff0000u)
            + w2 * __uint_as_float(p2 & 0xffff0000u) + w3 * __uint_as_float(p3 & 0xffff0000u);
    }
    for (; j < n; j++) {
        int s0 = __shfl(ce, j);
        float w0 = __shfl(we, j);
        unsigned int p0 = *(const unsigned int*)&h[(size_t)s0 * 128 + lane * 2];
        ax += w0 * __uint_as_float(p0 << 16);
        ay += w0 * __uint_as_float(p0 & 0xffff0000u);
    }
    ax += b[lane * 2 + 0];
    ay += b[lane * 2 + 1];
    if (do_relu) { ax = fmaxf(ax, 0.0f); ay = fmaxf(ay, 0.0f); }
    float2 o; o.x = ax; o.y = ay;
    *(float2*)&outp[(size_t)node * 128 + lane * 2] = o;
}

// ------- pool stage 1: wave per node; ELL row + z gather + butterfly reduce -------
// lane < n: edge term (w,s from normalized ELL); lane == n: self term (dinv^2, node).
// lane 0 LDS-atomics the 10-vector into per-block bins; block writes bins to partial.
__global__ __launch_bounds__(256) void k_pool_node(const int* __restrict__ cnt,
                                                   const ull* __restrict__ ell,
                                                   const float* __restrict__ dinv,
                                                   const float* __restrict__ z,
                                                   const int* __restrict__ batch,
                                                   float* __restrict__ partial) {
    __shared__ float ls[NG * CO + NG];
    for (int i = threadIdx.x; i < NG * CO + NG; i += 256) ls[i] = 0.0f;
    __syncthreads();
    int lane = threadIdx.x & 63;
    int gwave = blockIdx.x * 4 + (threadIdx.x >> 6);
    for (int node = gwave; node < NN; node += NB * 4) {
        int n = cnt[node];
        float w = 0.0f; int s = 0;
        if (lane < n) {
            ull rec = ell[(size_t)node * CAP + lane];
            s = (int)(unsigned int)(rec & 0xffffffffu);
            w = __uint_as_float((unsigned int)(rec >> 32));
        } else if (lane == n) {
            s = node;
            float di = dinv[node];
            w = di * di;
        }
        const float* zp = &z[(size_t)s * 10];
        float v[10];
#pragma unroll
        for (int f = 0; f < 10; f++) v[f] = w * zp[f];
#pragma unroll
        for (int off = 32; off; off >>= 1) {
#pragma unroll
            for (int f = 0; f < 10; f++) v[f] += __shfl_down(v[f], off);
        }
        if (lane == 0) {
            int g = batch[node];
            float* lp = &ls[g * 10];
#pragma unroll
            for (int f = 0; f < 10; f++) atomicAdd(&lp[f], v[f]);
            atomicAdd(&ls[NG * CO + g], 1.0f);
        }
    }
    __syncthreads();
    float* pb = &partial[(size_t)blockIdx.x * (NG * CO + NG)];
    for (int i = threadIdx.x; i < NG * CO + NG; i += 256) pb[i] = ls[i];
}

// ------- pool stage 2 + log_softmax: one wave per graph, sum NB partials -------
__global__ void k_pool_final(const float* __restrict__ partial,
                             const float* __restrict__ b3,
                             float* __restrict__ out) {
    int g = blockIdx.x;
    int lane = threadIdx.x;
    float v[10]; float c = 0.0f;
#pragma unroll
    for (int f = 0; f < 10; f++) v[f] = 0.0f;
    for (int b = lane; b < NB; b += 64) {
        const float* pb = &partial[(size_t)b * (NG * CO + NG)];
#pragma unroll
        for (int f = 0; f < 10; f++) v[f] += pb[g * 10 + f];
        c += pb[NG * CO + g];
    }
#pragma unroll
    for (int off = 32; off; off >>= 1) {
#pragma unroll
        for (int f = 0; f < 10; f++) v[f] += __shfl_down(v[f], off);
        c += __shfl_down(c, off);
    }
    if (lane == 0) {
        c = fmaxf(c, 1.0f);
        float p[10], m = -1e30f;
#pragma unroll
        for (int f = 0; f < 10; f++) { p[f] = v[f] / c + b3[f]; m = fmaxf(m, p[f]); }
        float ssum = 0.0f;
#pragma unroll
        for (int f = 0; f < 10; f++) ssum += __expf(p[f] - m);
        float lse = m + __logf(ssum);
#pragma unroll
        for (int f = 0; f < 10; f++) out[g * 10 + f] = p[f] - lse;
    }
}

extern "C" void kernel_launch(void* const* d_in, const int* in_sizes, int n_in,
                              void* d_out, int out_size, void* d_ws, size_t ws_size,
                              hipStream_t stream) {
    const float* x     = (const float*)d_in[0];
    const int*   ei    = (const int*)d_in[1];     // [2, E]
    const float* ea    = (const float*)d_in[2];
    const int*   batch = (const int*)d_in[3];
    const float* W1    = (const float*)d_in[4];
    const float* b1    = (const float*)d_in[5];
    const float* W2    = (const float*)d_in[6];
    const float* b2    = (const float*)d_in[7];
    const float* W3    = (const float*)d_in[8];
    const float* b3    = (const float*)d_in[9];
    float* out = (float*)d_out;
    float* ws  = (float*)d_ws;

    const int* esrc = ei;
    const int* edst = ei + NE;

    // workspace layout (float offsets; all even -> 8B aligned)
    float*  bufA    = ws;                          // 6,400,000 floats
    ushort* hb      = (ushort*)(ws + 6400000);     // 6,400,000 ushorts = 3,200,000 floats
    float*  z       = ws + 9600000;                // 500,000 floats
    float*  dinv    = ws + 10100000;               // 50,000
    int*    cnt     = (int*)(ws + 10160000);       // 50,000 ints
    ull*    ell     = (ull*)(ws + 10210000);       // NN*CAP ulls = 6,400,000 floats
    float*  partial = ws + 16610000;               // NB*1408 = 720,896 floats

    // --- ELL build + normalization (1 atomic + one 8B store per edge) ---
    hipMemsetAsync(cnt, 0, NN * sizeof(int), stream);
    k_ell<<<(NE + 255) / 256, 256, 0, stream>>>(esrc, edst, ea, cnt, ell);
    k_deg<<<(NN + 3) / 4, 256, 0, stream>>>(cnt, ell, dinv);
    k_scale<<<(NN + 3) / 4, 256, 0, stream>>>(cnt, ell, dinv);

    // --- layer 1 ---
    k_gemm128<<<(NN + 63) / 64, 256, 0, stream>>>(x, W1, hb, NN);
    k_gather128<<<(NN + 3) / 4, 256, 0, stream>>>(cnt, ell, dinv, hb, b1, bufA, 1);

    // --- layer 2 ---
    k_gemm128<<<(NN + 63) / 64, 256, 0, stream>>>(bufA, W2, hb, NN);
    k_gather128<<<(NN + 3) / 4, 256, 0, stream>>>(cnt, ell, dinv, hb, b2, bufA, 1);

    // --- layer 3: z = bufA @ W3, then wave-per-node pool via normalized ELL ---
    k_gemm10<<<(NN + 15) / 16, 256, 0, stream>>>(bufA, W3, z, NN);
    k_pool_node<<<NB, 256, 0, stream>>>(cnt, ell, dinv, z, batch, partial);
    k_pool_final<<<NG, 64, 0, stream>>>(partial, b3, out);
}

// Round 8
// 335.454 us; speedup vs baseline: 1.0315x; 1.0315x over previous
//
#include <hip/hip_runtime.h>

#define NN 50000
#define NE 800000
#define NG 128
#define DIM 128
#define CO 10
#define CAP 64    // ELL row capacity; Poisson(16) tail beyond 64 is ~1e-20
#define NB 2048   // pool stage-1 blocks: 8192 waves ~= full occupancy

typedef unsigned long long ull;
typedef unsigned short ushort;

static __device__ __forceinline__ ushort f2bf(float f) {
    unsigned int u = __float_as_uint(f);
    unsigned int r = (u + 0x7FFF + ((u >> 16) & 1)) >> 16;   // RNE
    return (ushort)r;
}

// ---------------- ELL build: one pass, one atomic + one 8B store per edge ----------------
__global__ void k_ell(const int* __restrict__ src, const int* __restrict__ dst,
                      const float* __restrict__ ew, int* __restrict__ cnt,
                      ull* __restrict__ ell) {
    int e = blockIdx.x * blockDim.x + threadIdx.x;
    if (e >= NE) return;
    int d = dst[e], s = src[e];
    int slot = atomicAdd(&cnt[d], 1);
    if (slot < CAP) {
        ull rec = ((ull)__float_as_uint(ew[e]) << 32) | (unsigned int)s;
        ell[(size_t)d * CAP + slot] = rec;
    }
}

// ---------------- degree: wave per node, dinv = rsqrt(1 + sum ew) ----------------
__global__ __launch_bounds__(256) void k_deg(const int* __restrict__ cnt,
                                             const ull* __restrict__ ell,
                                             float* __restrict__ dinv) {
    int node = blockIdx.x * 4 + (threadIdx.x >> 6);
    int lane = threadIdx.x & 63;
    if (node >= NN) return;
    int n = cnt[node];
    float w = 0.0f;
    if (lane < n) w = __uint_as_float((unsigned int)(ell[(size_t)node * CAP + lane] >> 32));
#pragma unroll
    for (int off = 32; off; off >>= 1) w += __shfl_down(w, off);
    if (lane == 0) dinv[node] = rsqrtf(1.0f + w);
}

// ---------------- scale ew -> dinv[d]*ew*dinv[s], rewrite rec in place ----------------
__global__ __launch_bounds__(256) void k_scale(const int* __restrict__ cnt,
                                               ull* __restrict__ ell,
                                               const float* __restrict__ dinv) {
    int node = blockIdx.x * 4 + (threadIdx.x >> 6);
    int lane = threadIdx.x & 63;
    if (node >= NN) return;
    int n = cnt[node];
    if (lane >= n) return;
    size_t idx = (size_t)node * CAP + lane;
    ull rec = ell[idx];
    int s = (int)(unsigned int)(rec & 0xffffffffu);
    float ew = __uint_as_float((unsigned int)(rec >> 32));
    float v = dinv[node] * ew * dinv[s];
    ell[idx] = ((ull)__float_as_uint(v) << 32) | (unsigned int)s;
}

// ------- GEMM: C[M x 128](bf16) = A[M x 128](fp32) @ W[128 x 128](fp32) -------
__global__ __launch_bounds__(256) void k_gemm128(const float* __restrict__ A,
                                                 const float* __restrict__ W,
                                                 ushort* __restrict__ C, int M) {
    __shared__ float As[64][33];
    __shared__ float Bs[32][132];
    int tid = threadIdx.x;
    int block_row = blockIdx.x * 64;
    int tx = tid & 15;
    int ty = tid >> 4;
    int r0 = ty * 4;
    int c1 = tx * 4, c2 = 64 + tx * 4;
    float acc[4][8];
#pragma unroll
    for (int i = 0; i < 4; i++)
#pragma unroll
        for (int j = 0; j < 8; j++) acc[i][j] = 0.0f;

    for (int k0 = 0; k0 < 128; k0 += 32) {
#pragma unroll
        for (int l = 0; l < 2; l++) {
            int idx = tid + l * 256;
            int ar = idx >> 3;
            int ac = (idx & 7) * 4;
            int grow = block_row + ar;
            if (grow >= M) grow = M - 1;
            float4 v = *(const float4*)&A[(size_t)grow * 128 + k0 + ac];
            As[ar][ac + 0] = v.x; As[ar][ac + 1] = v.y;
            As[ar][ac + 2] = v.z; As[ar][ac + 3] = v.w;
        }
#pragma unroll
        for (int l = 0; l < 4; l++) {
            int idx = tid + l * 256;
            int br = idx >> 5;
            int bc = (idx & 31) * 4;
            float4 v = *(const float4*)&W[(size_t)(k0 + br) * 128 + bc];
            *(float4*)&Bs[br][bc] = v;
        }
        __syncthreads();
#pragma unroll
        for (int kk = 0; kk < 32; kk++) {
            float a0 = As[r0 + 0][kk];
            float a1 = As[r0 + 1][kk];
            float a2 = As[r0 + 2][kk];
            float a3 = As[r0 + 3][kk];
            float4 bl = *(float4*)&Bs[kk][c1];
            float4 bh = *(float4*)&Bs[kk][c2];
            acc[0][0] += a0 * bl.x; acc[0][1] += a0 * bl.y; acc[0][2] += a0 * bl.z; acc[0][3] += a0 * bl.w;
            acc[0][4] += a0 * bh.x; acc[0][5] += a0 * bh.y; acc[0][6] += a0 * bh.z; acc[0][7] += a0 * bh.w;
            acc[1][0] += a1 * bl.x; acc[1][1] += a1 * bl.y; acc[1][2] += a1 * bl.z; acc[1][3] += a1 * bl.w;
            acc[1][4] += a1 * bh.x; acc[1][5] += a1 * bh.y; acc[1][6] += a1 * bh.z; acc[1][7] += a1 * bh.w;
            acc[2][0] += a2 * bl.x; acc[2][1] += a2 * bl.y; acc[2][2] += a2 * bl.z; acc[2][3] += a2 * bl.w;
            acc[2][4] += a2 * bh.x; acc[2][5] += a2 * bh.y; acc[2][6] += a2 * bh.z; acc[2][7] += a2 * bh.w;
            acc[3][0] += a3 * bl.x; acc[3][1] += a3 * bl.y; acc[3][2] += a3 * bl.z; acc[3][3] += a3 * bl.w;
            acc[3][4] += a3 * bh.x; acc[3][5] += a3 * bh.y; acc[3][6] += a3 * bh.z; acc[3][7] += a3 * bh.w;
        }
        __syncthreads();
    }
#pragma unroll
    for (int i = 0; i < 4; i++) {
        int grow = block_row + r0 + i;
        if (grow < M) {
            ushort4 u1, u2;
            u1.x = f2bf(acc[i][0]); u1.y = f2bf(acc[i][1]); u1.z = f2bf(acc[i][2]); u1.w = f2bf(acc[i][3]);
            u2.x = f2bf(acc[i][4]); u2.y = f2bf(acc[i][5]); u2.z = f2bf(acc[i][6]); u2.w = f2bf(acc[i][7]);
            *(ushort4*)&C[(size_t)grow * 128 + c1] = u1;
            *(ushort4*)&C[(size_t)grow * 128 + c2] = u2;
        }
    }
}

// ---------------- GEMM3: z[M x 10](fp32) = A[M x 128](fp32) @ W3[128 x 10] ----------------
__global__ __launch_bounds__(256) void k_gemm10(const float* __restrict__ A,
                                                const float* __restrict__ W3,
                                                float* __restrict__ C3, int M) {
    __shared__ float Ws[1280];
    int tid = threadIdx.x;
    for (int i = tid; i < 1280; i += 256) Ws[i] = W3[i];
    __syncthreads();
    int col = tid & 15;
    int rloc = tid >> 4;
    int row = blockIdx.x * 16 + rloc;
    if (row >= M || col >= 10) return;
    const float* a = &A[(size_t)row * 128];
    float acc = 0.0f;
#pragma unroll
    for (int k = 0; k < 128; k += 4) {
        float4 av = *(const float4*)&a[k];
        acc += av.x * Ws[(k + 0) * 10 + col];
        acc += av.y * Ws[(k + 1) * 10 + col];
        acc += av.z * Ws[(k + 2) * 10 + col];
        acc += av.w * Ws[(k + 3) * 10 + col];
    }
    C3[(size_t)row * 10 + col] = acc;
}

// ---- ELL gather: one wave/node, bf16 h, packed rec + shfl broadcast, fp32 accum ----
__global__ __launch_bounds__(256) void k_gather128(const int* __restrict__ cnt,
                                                   const ull* __restrict__ ell,
                                                   const float* __restrict__ dinv,
                                                   const ushort* __restrict__ h,
                                                   const float* __restrict__ b,
                                                   float* __restrict__ outp,
                                                   int do_relu) {
    int node = blockIdx.x * 4 + (threadIdx.x >> 6);
    int lane = threadIdx.x & 63;
    if (node >= NN) return;
    int n = cnt[node];
    float di = dinv[node];
    unsigned int hp = *(const unsigned int*)&h[(size_t)node * 128 + lane * 2];
    float ax = di * di * __uint_as_float(hp << 16);
    float ay = di * di * __uint_as_float(hp & 0xffff0000u);
    ull rec = ell[(size_t)node * CAP + lane];
    int ce = (int)(unsigned int)(rec & 0xffffffffu);
    float we = __uint_as_float((unsigned int)(rec >> 32));
    int j = 0;
    for (; j + 3 < n; j += 4) {
        int s0 = __shfl(ce, j + 0), s1 = __shfl(ce, j + 1);
        int s2 = __shfl(ce, j + 2), s3 = __shfl(ce, j + 3);
        float w0 = __shfl(we, j + 0), w1 = __shfl(we, j + 1);
        float w2 = __shfl(we, j + 2), w3 = __shfl(we, j + 3);
        unsigned int p0 = *(const unsigned int*)&h[(size_t)s0 * 128 + lane * 2];
        unsigned int p1 = *(const unsigned int*)&h[(size_t)s1 * 128 + lane * 2];
        unsigned int p2 = *(const unsigned int*)&h[(size_t)s2 * 128 + lane * 2];
        unsigned int p3 = *(const unsigned int*)&h[(size_t)s3 * 128 + lane * 2];
        ax += w0 * __uint_as_float(p0 << 16) + w1 * __uint_as_float(p1 << 16)
            + w2 * __uint_as_float(p2 << 16) + w3 * __uint_as_float(p3 << 16);
        ay += w0 * __uint_as_float(p0 & 0xffff0000u) + w1 * __uint_as_float(p1 & 0xffff0000u)
            + w2 * __uint_as_float(p2 & 0xffff0000u) + w3 * __uint_as_float(p3 & 0xffff0000u);
    }
    for (; j < n; j++) {
        int s0 = __shfl(ce, j);
        float w0 = __shfl(we, j);
        unsigned int p0 = *(const unsigned int*)&h[(size_t)s0 * 128 + lane * 2];
        ax += w0 * __uint_as_float(p0 << 16);
        ay += w0 * __uint_as_float(p0 & 0xffff0000u);
    }
    ax += b[lane * 2 + 0];
    ay += b[lane * 2 + 1];
    if (do_relu) { ax = fmaxf(ax, 0.0f); ay = fmaxf(ay, 0.0f); }
    float2 o; o.x = ax; o.y = ay;
    *(float2*)&outp[(size_t)node * 128 + lane * 2] = o;
}

// ------- pool stage 1: wave per node; ELL row + z gather + butterfly reduce -------
__global__ __launch_bounds__(256) void k_pool_node(const int* __restrict__ cnt,
                                                   const ull* __restrict__ ell,
                                                   const float* __restrict__ dinv,
                                                   const float* __restrict__ z,
                                                   const int* __restrict__ batch,
                                                   float* __restrict__ partial) {
    __shared__ float ls[NG * CO + NG];
    for (int i = threadIdx.x; i < NG * CO + NG; i += 256) ls[i] = 0.0f;
    __syncthreads();
    int lane = threadIdx.x & 63;
    int gwave = blockIdx.x * 4 + (threadIdx.x >> 6);
    for (int node = gwave; node < NN; node += NB * 4) {
        int n = cnt[node];
        float w = 0.0f; int s = 0;
        if (lane < n) {
            ull rec = ell[(size_t)node * CAP + lane];
            s = (int)(unsigned int)(rec & 0xffffffffu);
            w = __uint_as_float((unsigned int)(rec >> 32));
        } else if (lane == n) {
            s = node;
            float di = dinv[node];
            w = di * di;
        }
        const float* zp = &z[(size_t)s * 10];
        float v[10];
#pragma unroll
        for (int f = 0; f < 10; f++) v[f] = w * zp[f];
#pragma unroll
        for (int off = 32; off; off >>= 1) {
#pragma unroll
            for (int f = 0; f < 10; f++) v[f] += __shfl_down(v[f], off);
        }
        if (lane == 0) {
            int g = batch[node];
            float* lp = &ls[g * 10];
#pragma unroll
            for (int f = 0; f < 10; f++) atomicAdd(&lp[f], v[f]);
            atomicAdd(&ls[NG * CO + g], 1.0f);
        }
    }
    __syncthreads();
    float* pb = &partial[(size_t)blockIdx.x * (NG * CO + NG)];
    for (int i = threadIdx.x; i < NG * CO + NG; i += 256) pb[i] = ls[i];
}

// ------- pool stage 2 + log_softmax: one block (256 thr) per graph -------
__global__ __launch_bounds__(256) void k_pool_final(const float* __restrict__ partial,
                                                    const float* __restrict__ b3,
                                                    float* __restrict__ out) {
    __shared__ float red[4][11];
    int g = blockIdx.x;
    int t = threadIdx.x;
    int lane = t & 63, wv = t >> 6;
    float v[10]; float c = 0.0f;
#pragma unroll
    for (int f = 0; f < 10; f++) v[f] = 0.0f;
    for (int b = t; b < NB; b += 256) {
        const float* pb = &partial[(size_t)b * (NG * CO + NG)];
#pragma unroll
        for (int f = 0; f < 10; f++) v[f] += pb[g * 10 + f];
        c += pb[NG * CO + g];
    }
#pragma unroll
    for (int off = 32; off; off >>= 1) {
#pragma unroll
        for (int f = 0; f < 10; f++) v[f] += __shfl_down(v[f], off);
        c += __shfl_down(c, off);
    }
    if (lane == 0) {
#pragma unroll
        for (int f = 0; f < 10; f++) red[wv][f] = v[f];
        red[wv][10] = c;
    }
    __syncthreads();
    if (t == 0) {
        float p[10], m = -1e30f;
        float cc = red[0][10] + red[1][10] + red[2][10] + red[3][10];
        cc = fmaxf(cc, 1.0f);
#pragma unroll
        for (int f = 0; f < 10; f++) {
            p[f] = (red[0][f] + red[1][f] + red[2][f] + red[3][f]) / cc + b3[f];
            m = fmaxf(m, p[f]);
        }
        float ssum = 0.0f;
#pragma unroll
        for (int f = 0; f < 10; f++) ssum += __expf(p[f] - m);
        float lse = m + __logf(ssum);
#pragma unroll
        for (int f = 0; f < 10; f++) out[g * 10 + f] = p[f] - lse;
    }
}

extern "C" void kernel_launch(void* const* d_in, const int* in_sizes, int n_in,
                              void* d_out, int out_size, void* d_ws, size_t ws_size,
                              hipStream_t stream) {
    const float* x     = (const float*)d_in[0];
    const int*   ei    = (const int*)d_in[1];     // [2, E]
    const float* ea    = (const float*)d_in[2];
    const int*   batch = (const int*)d_in[3];
    const float* W1    = (const float*)d_in[4];
    const float* b1    = (const float*)d_in[5];
    const float* W2    = (const float*)d_in[6];
    const float* b2    = (const float*)d_in[7];
    const float* W3    = (const float*)d_in[8];
    const float* b3    = (const float*)d_in[9];
    float* out = (float*)d_out;
    float* ws  = (float*)d_ws;

    const int* esrc = ei;
    const int* edst = ei + NE;

    // workspace layout (float offsets; all even -> 8B aligned)
    float*  bufA    = ws;                          // 6,400,000 floats
    ushort* hb      = (ushort*)(ws + 6400000);     // 6,400,000 ushorts = 3,200,000 floats
    float*  z       = ws + 9600000;                // 500,000 floats
    float*  dinv    = ws + 10100000;               // 50,000
    int*    cnt     = (int*)(ws + 10160000);       // 50,000 ints
    ull*    ell     = (ull*)(ws + 10210000);       // NN*CAP ulls = 6,400,000 floats
    float*  partial = bufA;                        // NB*1408 = 2,883,584 floats, overlays bufA
                                                   // (bufA is dead after k_gemm10 reads it)

    // --- ELL build + normalization (1 atomic + one 8B store per edge) ---
    hipMemsetAsync(cnt, 0, NN * sizeof(int), stream);
    k_ell<<<(NE + 255) / 256, 256, 0, stream>>>(esrc, edst, ea, cnt, ell);
    k_deg<<<(NN + 3) / 4, 256, 0, stream>>>(cnt, ell, dinv);
    k_scale<<<(NN + 3) / 4, 256, 0, stream>>>(cnt, ell, dinv);

    // --- layer 1 ---
    k_gemm128<<<(NN + 63) / 64, 256, 0, stream>>>(x, W1, hb, NN);
    k_gather128<<<(NN + 3) / 4, 256, 0, stream>>>(cnt, ell, dinv, hb, b1, bufA, 1);

    // --- layer 2 ---
    k_gemm128<<<(NN + 63) / 64, 256, 0, stream>>>(bufA, W2, hb, NN);
    k_gather128<<<(NN + 3) / 4, 256, 0, stream>>>(cnt, ell, dinv, hb, b2, bufA, 1);

    // --- layer 3: z = bufA @ W3, then wave-per-node pool via normalized ELL ---
    k_gemm10<<<(NN + 15) / 16, 256, 0, stream>>>(bufA, W3, z, NN);
    k_pool_node<<<NB, 256, 0, stream>>>(cnt, ell, dinv, z, batch, partial);
    k_pool_final<<<NG, 256, 0, stream>>>(partial, b3, out);
}

// Round 9
// 325.704 us; speedup vs baseline: 1.0624x; 1.0299x over previous
//
#include <hip/hip_runtime.h>

#define NN 50000
#define NE 800000
#define NG 128
#define DIM 128
#define CO 10
#define CAP 64    // ELL row capacity; Poisson(16) tail beyond 64 is ~1e-20
#define NB 2048   // pool stage-1 blocks

typedef unsigned long long ull;
typedef unsigned short ushort;
typedef unsigned int uint;

static __device__ __forceinline__ ushort f2bf(float f) {
    uint u = __float_as_uint(f);
    uint r = (u + 0x7FFF + ((u >> 16) & 1)) >> 16;   // RNE
    return (ushort)r;
}
#define EWS (1.0f / 65535.0f)

// ---- ELL build: 4B record (ew_u16 << 16 | src_u16), one atomic + one 4B store ----
__global__ void k_ell(const int* __restrict__ src, const int* __restrict__ dst,
                      const float* __restrict__ ew, int* __restrict__ cnt,
                      uint* __restrict__ ell) {
    int e = blockIdx.x * blockDim.x + threadIdx.x;
    if (e >= NE) return;
    int d = dst[e], s = src[e];
    int slot = atomicAdd(&cnt[d], 1);
    if (slot < CAP) {
        uint w16 = (uint)__float2uint_rn(ew[e] * 65535.0f);
        ell[(size_t)d * CAP + slot] = (w16 << 16) | (uint)s;
    }
}

// ---- degree: wave per node, dinv = rsqrt(1 + sum ew) ----
__global__ __launch_bounds__(256) void k_deg(const int* __restrict__ cnt,
                                             const uint* __restrict__ ell,
                                             float* __restrict__ dinv) {
    int node = blockIdx.x * 4 + (threadIdx.x >> 6);
    int lane = threadIdx.x & 63;
    if (node >= NN) return;
    int n = cnt[node];
    float w = 0.0f;
    if (lane < n) w = (float)(ell[(size_t)node * CAP + lane] >> 16) * EWS;
#pragma unroll
    for (int off = 32; off; off >>= 1) w += __shfl_down(w, off);
    if (lane == 0) dinv[node] = rsqrtf(1.0f + w);
}

// ---- GEMM: C[M x 128](bf16) = dinv ⊙ (A[M x 128] @ W[128 x 128]) ; A fp32 or bf16 ----
__global__ __launch_bounds__(256) void k_gemm128(const void* __restrict__ Ain, int abf,
                                                 const float* __restrict__ W,
                                                 const float* __restrict__ dinv,
                                                 ushort* __restrict__ C, int M) {
    __shared__ float As[64][33];
    __shared__ float Bs[32][132];
    int tid = threadIdx.x;
    int block_row = blockIdx.x * 64;
    int tx = tid & 15;
    int ty = tid >> 4;
    int r0 = ty * 4;
    int c1 = tx * 4, c2 = 64 + tx * 4;
    float acc[4][8];
#pragma unroll
    for (int i = 0; i < 4; i++)
#pragma unroll
        for (int j = 0; j < 8; j++) acc[i][j] = 0.0f;

    for (int k0 = 0; k0 < 128; k0 += 32) {
        if (abf) {
            const ushort* Ab = (const ushort*)Ain;
            int ar = tid >> 2;
            int ac = (tid & 3) * 8;
            int grow = block_row + ar;
            if (grow >= M) grow = M - 1;
            uint4 v = *(const uint4*)&Ab[(size_t)grow * 128 + k0 + ac];
            As[ar][ac + 0] = __uint_as_float(v.x << 16);
            As[ar][ac + 1] = __uint_as_float(v.x & 0xffff0000u);
            As[ar][ac + 2] = __uint_as_float(v.y << 16);
            As[ar][ac + 3] = __uint_as_float(v.y & 0xffff0000u);
            As[ar][ac + 4] = __uint_as_float(v.z << 16);
            As[ar][ac + 5] = __uint_as_float(v.z & 0xffff0000u);
            As[ar][ac + 6] = __uint_as_float(v.w << 16);
            As[ar][ac + 7] = __uint_as_float(v.w & 0xffff0000u);
        } else {
            const float* Af = (const float*)Ain;
#pragma unroll
            for (int l = 0; l < 2; l++) {
                int idx = tid + l * 256;
                int ar = idx >> 3;
                int ac = (idx & 7) * 4;
                int grow = block_row + ar;
                if (grow >= M) grow = M - 1;
                float4 v = *(const float4*)&Af[(size_t)grow * 128 + k0 + ac];
                As[ar][ac + 0] = v.x; As[ar][ac + 1] = v.y;
                As[ar][ac + 2] = v.z; As[ar][ac + 3] = v.w;
            }
        }
#pragma unroll
        for (int l = 0; l < 4; l++) {
            int idx = tid + l * 256;
            int br = idx >> 5;
            int bc = (idx & 31) * 4;
            float4 v = *(const float4*)&W[(size_t)(k0 + br) * 128 + bc];
            *(float4*)&Bs[br][bc] = v;
        }
        __syncthreads();
#pragma unroll
        for (int kk = 0; kk < 32; kk++) {
            float a0 = As[r0 + 0][kk];
            float a1 = As[r0 + 1][kk];
            float a2 = As[r0 + 2][kk];
            float a3 = As[r0 + 3][kk];
            float4 bl = *(float4*)&Bs[kk][c1];
            float4 bh = *(float4*)&Bs[kk][c2];
            acc[0][0] += a0 * bl.x; acc[0][1] += a0 * bl.y; acc[0][2] += a0 * bl.z; acc[0][3] += a0 * bl.w;
            acc[0][4] += a0 * bh.x; acc[0][5] += a0 * bh.y; acc[0][6] += a0 * bh.z; acc[0][7] += a0 * bh.w;
            acc[1][0] += a1 * bl.x; acc[1][1] += a1 * bl.y; acc[1][2] += a1 * bl.z; acc[1][3] += a1 * bl.w;
            acc[1][4] += a1 * bh.x; acc[1][5] += a1 * bh.y; acc[1][6] += a1 * bh.z; acc[1][7] += a1 * bh.w;
            acc[2][0] += a2 * bl.x; acc[2][1] += a2 * bl.y; acc[2][2] += a2 * bl.z; acc[2][3] += a2 * bl.w;
            acc[2][4] += a2 * bh.x; acc[2][5] += a2 * bh.y; acc[2][6] += a2 * bh.z; acc[2][7] += a2 * bh.w;
            acc[3][0] += a3 * bl.x; acc[3][1] += a3 * bl.y; acc[3][2] += a3 * bl.z; acc[3][3] += a3 * bl.w;
            acc[3][4] += a3 * bh.x; acc[3][5] += a3 * bh.y; acc[3][6] += a3 * bh.z; acc[3][7] += a3 * bh.w;
        }
        __syncthreads();
    }
#pragma unroll
    for (int i = 0; i < 4; i++) {
        int grow = block_row + r0 + i;
        if (grow < M) {
            float di = dinv[grow];
            ushort4 u1, u2;
            u1.x = f2bf(di * acc[i][0]); u1.y = f2bf(di * acc[i][1]);
            u1.z = f2bf(di * acc[i][2]); u1.w = f2bf(di * acc[i][3]);
            u2.x = f2bf(di * acc[i][4]); u2.y = f2bf(di * acc[i][5]);
            u2.z = f2bf(di * acc[i][6]); u2.w = f2bf(di * acc[i][7]);
            *(ushort4*)&C[(size_t)grow * 128 + c1] = u1;
            *(ushort4*)&C[(size_t)grow * 128 + c2] = u2;
        }
    }
}

// ---- GEMM3: z'[M x 10](fp32) = dinv ⊙ (A[M x 128](bf16) @ W3[128 x 10]) ----
__global__ __launch_bounds__(256) void k_gemm10(const ushort* __restrict__ A,
                                                const float* __restrict__ W3,
                                                const float* __restrict__ dinv,
                                                float* __restrict__ C3, int M) {
    __shared__ float Ws[1280];
    int tid = threadIdx.x;
    for (int i = tid; i < 1280; i += 256) Ws[i] = W3[i];
    __syncthreads();
    int col = tid & 15;
    int rloc = tid >> 4;
    int row = blockIdx.x * 16 + rloc;
    if (row >= M || col >= 10) return;
    const ushort* a = &A[(size_t)row * 128];
    float acc = 0.0f;
#pragma unroll
    for (int k = 0; k < 128; k += 4) {
        ushort4 av = *(const ushort4*)&a[k];
        acc += __uint_as_float((uint)av.x << 16) * Ws[(k + 0) * 10 + col];
        acc += __uint_as_float((uint)av.y << 16) * Ws[(k + 1) * 10 + col];
        acc += __uint_as_float((uint)av.z << 16) * Ws[(k + 2) * 10 + col];
        acc += __uint_as_float((uint)av.w << 16) * Ws[(k + 3) * 10 + col];
    }
    C3[(size_t)row * 10 + col] = dinv[row] * acc;
}

// ---- ELL gather: out = bf16(relu(dinv_d*(sum ew*h'[s] + h'[d]) + b)) ----
__global__ __launch_bounds__(256) void k_gather128(const int* __restrict__ cnt,
                                                   const uint* __restrict__ ell,
                                                   const float* __restrict__ dinv,
                                                   const ushort* __restrict__ h,
                                                   const float* __restrict__ b,
                                                   ushort* __restrict__ outp) {
    int node = blockIdx.x * 4 + (threadIdx.x >> 6);
    int lane = threadIdx.x & 63;
    if (node >= NN) return;
    int n = cnt[node];
    uint hp = *(const uint*)&h[(size_t)node * 128 + lane * 2];
    float ax = __uint_as_float(hp << 16);          // self term: h'[d], weight 1
    float ay = __uint_as_float(hp & 0xffff0000u);
    uint rec = ell[(size_t)node * CAP + lane];
    int ce = (int)(rec & 0xffffu);
    float we = (float)(rec >> 16) * EWS;
    int j = 0;
    for (; j + 3 < n; j += 4) {
        int s0 = __shfl(ce, j + 0), s1 = __shfl(ce, j + 1);
        int s2 = __shfl(ce, j + 2), s3 = __shfl(ce, j + 3);
        float w0 = __shfl(we, j + 0), w1 = __shfl(we, j + 1);
        float w2 = __shfl(we, j + 2), w3 = __shfl(we, j + 3);
        uint p0 = *(const uint*)&h[(size_t)s0 * 128 + lane * 2];
        uint p1 = *(const uint*)&h[(size_t)s1 * 128 + lane * 2];
        uint p2 = *(const uint*)&h[(size_t)s2 * 128 + lane * 2];
        uint p3 = *(const uint*)&h[(size_t)s3 * 128 + lane * 2];
        ax += w0 * __uint_as_float(p0 << 16) + w1 * __uint_as_float(p1 << 16)
            + w2 * __uint_as_float(p2 << 16) + w3 * __uint_as_float(p3 << 16);
        ay += w0 * __uint_as_float(p0 & 0xffff0000u) + w1 * __uint_as_float(p1 & 0xffff0000u)
            + w2 * __uint_as_float(p2 & 0xffff0000u) + w3 * __uint_as_float(p3 & 0xffff0000u);
    }
    for (; j < n; j++) {
        int s0 = __shfl(ce, j);
        float w0 = __shfl(we, j);
        uint p0 = *(const uint*)&h[(size_t)s0 * 128 + lane * 2];
        ax += w0 * __uint_as_float(p0 << 16);
        ay += w0 * __uint_as_float(p0 & 0xffff0000u);
    }
    float di = dinv[node];
    ax = fmaxf(di * ax + b[lane * 2 + 0], 0.0f);
    ay = fmaxf(di * ay + b[lane * 2 + 1], 0.0f);
    uint o = ((uint)f2bf(ay) << 16) | (uint)f2bf(ax);
    *(uint*)&outp[(size_t)node * 128 + lane * 2] = o;
}

// ---- pool stage 1: wave per node; agg3[d] = dinv_d*(sum ew*z'[s] + z'[d]); pool by graph ----
__global__ __launch_bounds__(256) void k_pool_node(const int* __restrict__ cnt,
                                                   const uint* __restrict__ ell,
                                                   const float* __restrict__ dinv,
                                                   const float* __restrict__ z,
                                                   const int* __restrict__ batch,
                                                   float* __restrict__ partial) {
    __shared__ float ls[NG * CO + NG];
    for (int i = threadIdx.x; i < NG * CO + NG; i += 256) ls[i] = 0.0f;
    __syncthreads();
    int lane = threadIdx.x & 63;
    int gwave = blockIdx.x * 4 + (threadIdx.x >> 6);
    for (int node = gwave; node < NN; node += NB * 4) {
        int n = cnt[node];
        float w = 0.0f; int s = 0;
        if (lane < n) {
            uint rec = ell[(size_t)node * CAP + lane];
            s = (int)(rec & 0xffffu);
            w = (float)(rec >> 16) * EWS;
        } else if (lane == n) {
            s = node;
            w = 1.0f;                 // self term: z'[d]
        }
        const float* zp = &z[(size_t)s * 10];
        float v[10];
#pragma unroll
        for (int f = 0; f < 10; f++) v[f] = w * zp[f];
#pragma unroll
        for (int off = 32; off; off >>= 1) {
#pragma unroll
            for (int f = 0; f < 10; f++) v[f] += __shfl_down(v[f], off);
        }
        if (lane == 0) {
            int g = batch[node];
            float di = dinv[node];
            float* lp = &ls[g * 10];
#pragma unroll
            for (int f = 0; f < 10; f++) atomicAdd(&lp[f], di * v[f]);
            atomicAdd(&ls[NG * CO + g], 1.0f);
        }
    }
    __syncthreads();
    float* pb = &partial[(size_t)blockIdx.x * (NG * CO + NG)];
    for (int i = threadIdx.x; i < NG * CO + NG; i += 256) pb[i] = ls[i];
}

// ---- pool stage 2 + log_softmax: one block (256 thr) per graph ----
__global__ __launch_bounds__(256) void k_pool_final(const float* __restrict__ partial,
                                                    const float* __restrict__ b3,
                                                    float* __restrict__ out) {
    __shared__ float red[4][11];
    int g = blockIdx.x;
    int t = threadIdx.x;
    int lane = t & 63, wv = t >> 6;
    float v[10]; float c = 0.0f;
#pragma unroll
    for (int f = 0; f < 10; f++) v[f] = 0.0f;
    for (int b = t; b < NB; b += 256) {
        const float* pb = &partial[(size_t)b * (NG * CO + NG)];
#pragma unroll
        for (int f = 0; f < 10; f++) v[f] += pb[g * 10 + f];
        c += pb[NG * CO + g];
    }
#pragma unroll
    for (int off = 32; off; off >>= 1) {
#pragma unroll
        for (int f = 0; f < 10; f++) v[f] += __shfl_down(v[f], off);
        c += __shfl_down(c, off);
    }
    if (lane == 0) {
#pragma unroll
        for (int f = 0; f < 10; f++) red[wv][f] = v[f];
        red[wv][10] = c;
    }
    __syncthreads();
    if (t == 0) {
        float p[10], m = -1e30f;
        float cc = red[0][10] + red[1][10] + red[2][10] + red[3][10];
        cc = fmaxf(cc, 1.0f);
#pragma unroll
        for (int f = 0; f < 10; f++) {
            p[f] = (red[0][f] + red[1][f] + red[2][f] + red[3][f]) / cc + b3[f];
            m = fmaxf(m, p[f]);
        }
        float ssum = 0.0f;
#pragma unroll
        for (int f = 0; f < 10; f++) ssum += __expf(p[f] - m);
        float lse = m + __logf(ssum);
#pragma unroll
        for (int f = 0; f < 10; f++) out[g * 10 + f] = p[f] - lse;
    }
}

extern "C" void kernel_launch(void* const* d_in, const int* in_sizes, int n_in,
                              void* d_out, int out_size, void* d_ws, size_t ws_size,
                              hipStream_t stream) {
    const float* x     = (const float*)d_in[0];
    const int*   ei    = (const int*)d_in[1];     // [2, E]
    const float* ea    = (const float*)d_in[2];
    const int*   batch = (const int*)d_in[3];
    const float* W1    = (const float*)d_in[4];
    const float* b1    = (const float*)d_in[5];
    const float* W2    = (const float*)d_in[6];
    const float* b2    = (const float*)d_in[7];
    const float* W3    = (const float*)d_in[8];
    const float* b3    = (const float*)d_in[9];
    float* out = (float*)d_out;
    float* ws  = (float*)d_ws;

    const int* esrc = ei;
    const int* edst = ei + NE;

    // workspace layout (float offsets; all even -> 16B aligned)
    ushort* hb      = (ushort*)ws;                 // N*128 bf16 = 3,200,000 floats
    ushort* gb      = (ushort*)(ws + 3200000);     // N*128 bf16 = 3,200,000 floats
    float*  z       = ws + 6400000;                // 500,000
    float*  dinv    = ws + 6900000;                // 50,000
    int*    cnt     = (int*)(ws + 6950000);        // 50,000 ints
    uint*   ell     = (uint*)(ws + 7000000);       // NN*CAP u32 = 3,200,000
    float*  partial = (float*)hb;                  // NB*1408 = 2,883,584 floats, overlays hb
                                                   // (hb dead after gather-2)

    // --- ELL build + normalization ---
    hipMemsetAsync(cnt, 0, NN * sizeof(int), stream);
    k_ell<<<(NE + 255) / 256, 256, 0, stream>>>(esrc, edst, ea, cnt, ell);
    k_deg<<<(NN + 3) / 4, 256, 0, stream>>>(cnt, ell, dinv);

    // --- layer 1: h' = dinv*(X@W1) ; gather -> gb (bf16) ---
    k_gemm128<<<(NN + 63) / 64, 256, 0, stream>>>(x, 0, W1, dinv, hb, NN);
    k_gather128<<<(NN + 3) / 4, 256, 0, stream>>>(cnt, ell, dinv, hb, b1, gb);

    // --- layer 2 ---
    k_gemm128<<<(NN + 63) / 64, 256, 0, stream>>>(gb, 1, W2, dinv, hb, NN);
    k_gather128<<<(NN + 3) / 4, 256, 0, stream>>>(cnt, ell, dinv, hb, b2, gb);

    // --- layer 3: z' = dinv*(gb@W3), pool over nodes ---
    k_gemm10<<<(NN + 15) / 16, 256, 0, stream>>>(gb, W3, dinv, z, NN);
    k_pool_node<<<NB, 256, 0, stream>>>(cnt, ell, dinv, z, batch, partial);
    k_pool_final<<<NG, 256, 0, stream>>>(partial, b3, out);
}

// Round 10
// 312.525 us; speedup vs baseline: 1.1072x; 1.0422x over previous
//
#include <hip/hip_runtime.h>

#define NN 50000
#define NE 800000
#define NG 128
#define DIM 128
#define CO 10
#define CAP 64    // ELL row capacity; Poisson(16) tail beyond 64 is ~1e-20
#define NB 2048   // pool stage-1 blocks

typedef unsigned long long ull;
typedef unsigned short ushort;
typedef unsigned int uint;
typedef __attribute__((ext_vector_type(8))) short short8;   // 8 bf16 (4 VGPRs)
typedef __attribute__((ext_vector_type(4))) float floatx4;

static __device__ __forceinline__ ushort f2bf(float f) {
    uint u = __float_as_uint(f);
    uint r = (u + 0x7FFF + ((u >> 16) & 1)) >> 16;   // RNE
    return (ushort)r;
}
#define EWS (1.0f / 65535.0f)

// ---- ELL build: 4B record (ew_u16 << 16 | src_u16), one atomic + one 4B store ----
__global__ void k_ell(const int* __restrict__ src, const int* __restrict__ dst,
                      const float* __restrict__ ew, int* __restrict__ cnt,
                      uint* __restrict__ ell) {
    int e = blockIdx.x * blockDim.x + threadIdx.x;
    if (e >= NE) return;
    int d = dst[e], s = src[e];
    int slot = atomicAdd(&cnt[d], 1);
    if (slot < CAP) {
        uint w16 = (uint)__float2uint_rn(ew[e] * 65535.0f);
        ell[(size_t)d * CAP + slot] = (w16 << 16) | (uint)s;
    }
}

// ---- degree: wave per node, dinv = rsqrt(1 + sum ew) ----
__global__ __launch_bounds__(256) void k_deg(const int* __restrict__ cnt,
                                             const uint* __restrict__ ell,
                                             float* __restrict__ dinv) {
    int node = blockIdx.x * 4 + (threadIdx.x >> 6);
    int lane = threadIdx.x & 63;
    if (node >= NN) return;
    int n = cnt[node];
    float w = 0.0f;
    if (lane < n) w = (float)(ell[(size_t)node * CAP + lane] >> 16) * EWS;
#pragma unroll
    for (int off = 32; off; off >>= 1) w += __shfl_down(w, off);
    if (lane == 0) dinv[node] = rsqrtf(1.0f + w);
}

// ---- W prep: Wt[n][k] = bf16(W[k][n]), 128x128 ----
__global__ void k_prepw(const float* __restrict__ W, ushort* __restrict__ Wt) {
    int i = blockIdx.x * blockDim.x + threadIdx.x;   // 16384
    int k = i >> 7, n = i & 127;
    Wt[n * 128 + k] = f2bf(W[i]);
}

// ---- MFMA GEMM: C[M x 128](bf16) = dinv ⊙ (A[M x 128] @ W) ; A fp32 or bf16 ----
// Block = 256 thr = 4 waves; wave computes 16 rows x 128 cols via 8 n-tiles x 4 k-iters
// of v_mfma_f32_16x16x32_bf16. A-frag: A[m=lane&15][k=quad*8+j] (contiguous 16B/lane).
// B-frag from Wt[n][k]: Wt[n0+(lane&15)][k0+quad*8+j] (contiguous 16B/lane, L1-hot).
// C/D layout: col=lane&15, row=quad*4+reg (verified m89/m91).
__global__ __launch_bounds__(256) void k_gemm_mfma(const void* __restrict__ Ain, int abf,
                                                   const ushort* __restrict__ Wt,
                                                   const float* __restrict__ dinv,
                                                   ushort* __restrict__ C, int M) {
    int wave = threadIdx.x >> 6;
    int lane = threadIdx.x & 63;
    int quad = lane >> 4;
    int mcol = lane & 15;
    int r0 = blockIdx.x * 64 + wave * 16;
    int arow = r0 + mcol;
    if (arow >= M) arow = M - 1;
    floatx4 acc[8];
#pragma unroll
    for (int t = 0; t < 8; t++) acc[t] = (floatx4){0.0f, 0.0f, 0.0f, 0.0f};

    const ushort* Ab = (const ushort*)Ain;
    const float*  Af = (const float*)Ain;
#pragma unroll
    for (int kk = 0; kk < 4; kk++) {
        int koff = kk * 32 + quad * 8;
        short8 a;
        if (abf) {
            a = *(const short8*)&Ab[(size_t)arow * 128 + koff];
        } else {
            const float* ap = &Af[(size_t)arow * 128 + koff];
            float4 x0 = *(const float4*)ap;
            float4 x1 = *(const float4*)(ap + 4);
            union { short8 v; ushort u[8]; } ua;
            ua.u[0] = f2bf(x0.x); ua.u[1] = f2bf(x0.y); ua.u[2] = f2bf(x0.z); ua.u[3] = f2bf(x0.w);
            ua.u[4] = f2bf(x1.x); ua.u[5] = f2bf(x1.y); ua.u[6] = f2bf(x1.z); ua.u[7] = f2bf(x1.w);
            a = ua.v;
        }
#pragma unroll
        for (int t = 0; t < 8; t++) {
            short8 b = *(const short8*)&Wt[(size_t)(t * 16 + mcol) * 128 + koff];
            acc[t] = __builtin_amdgcn_mfma_f32_16x16x32_bf16(a, b, acc[t], 0, 0, 0);
        }
    }
#pragma unroll
    for (int reg = 0; reg < 4; reg++) {
        int row = r0 + quad * 4 + reg;
        if (row < M) {
            float di = dinv[row];
            ushort* cp = &C[(size_t)row * 128];
#pragma unroll
            for (int t = 0; t < 8; t++) cp[t * 16 + mcol] = f2bf(di * acc[t][reg]);
        }
    }
}

// ---- GEMM3: z'[M x 10](fp32) = dinv ⊙ (A[M x 128](bf16) @ W3[128 x 10]) ----
__global__ __launch_bounds__(256) void k_gemm10(const ushort* __restrict__ A,
                                                const float* __restrict__ W3,
                                                const float* __restrict__ dinv,
                                                float* __restrict__ C3, int M) {
    __shared__ float Ws[1280];
    int tid = threadIdx.x;
    for (int i = tid; i < 1280; i += 256) Ws[i] = W3[i];
    __syncthreads();
    int col = tid & 15;
    int rloc = tid >> 4;
    int row = blockIdx.x * 16 + rloc;
    if (row >= M || col >= 10) return;
    const ushort* a = &A[(size_t)row * 128];
    float acc = 0.0f;
#pragma unroll
    for (int k = 0; k < 128; k += 4) {
        ushort4 av = *(const ushort4*)&a[k];
        acc += __uint_as_float((uint)av.x << 16) * Ws[(k + 0) * 10 + col];
        acc += __uint_as_float((uint)av.y << 16) * Ws[(k + 1) * 10 + col];
        acc += __uint_as_float((uint)av.z << 16) * Ws[(k + 2) * 10 + col];
        acc += __uint_as_float((uint)av.w << 16) * Ws[(k + 3) * 10 + col];
    }
    C3[(size_t)row * 10 + col] = dinv[row] * acc;
}

// ---- ELL gather: out = bf16(relu(dinv_d*(sum ew*h'[s] + h'[d]) + b)) ----
__global__ __launch_bounds__(256) void k_gather128(const int* __restrict__ cnt,
                                                   const uint* __restrict__ ell,
                                                   const float* __restrict__ dinv,
                                                   const ushort* __restrict__ h,
                                                   const float* __restrict__ b,
                                                   ushort* __restrict__ outp) {
    int node = blockIdx.x * 4 + (threadIdx.x >> 6);
    int lane = threadIdx.x & 63;
    if (node >= NN) return;
    int n = cnt[node];
    uint hp = *(const uint*)&h[(size_t)node * 128 + lane * 2];
    float ax = __uint_as_float(hp << 16);          // self term: h'[d], weight 1
    float ay = __uint_as_float(hp & 0xffff0000u);
    uint rec = ell[(size_t)node * CAP + lane];
    int ce = (int)(rec & 0xffffu);
    float we = (float)(rec >> 16) * EWS;
    int j = 0;
    for (; j + 3 < n; j += 4) {
        int s0 = __shfl(ce, j + 0), s1 = __shfl(ce, j + 1);
        int s2 = __shfl(ce, j + 2), s3 = __shfl(ce, j + 3);
        float w0 = __shfl(we, j + 0), w1 = __shfl(we, j + 1);
        float w2 = __shfl(we, j + 2), w3 = __shfl(we, j + 3);
        uint p0 = *(const uint*)&h[(size_t)s0 * 128 + lane * 2];
        uint p1 = *(const uint*)&h[(size_t)s1 * 128 + lane * 2];
        uint p2 = *(const uint*)&h[(size_t)s2 * 128 + lane * 2];
        uint p3 = *(const uint*)&h[(size_t)s3 * 128 + lane * 2];
        ax += w0 * __uint_as_float(p0 << 16) + w1 * __uint_as_float(p1 << 16)
            + w2 * __uint_as_float(p2 << 16) + w3 * __uint_as_float(p3 << 16);
        ay += w0 * __uint_as_float(p0 & 0xffff0000u) + w1 * __uint_as_float(p1 & 0xffff0000u)
            + w2 * __uint_as_float(p2 & 0xffff0000u) + w3 * __uint_as_float(p3 & 0xffff0000u);
    }
    for (; j < n; j++) {
        int s0 = __shfl(ce, j);
        float w0 = __shfl(we, j);
        uint p0 = *(const uint*)&h[(size_t)s0 * 128 + lane * 2];
        ax += w0 * __uint_as_float(p0 << 16);
        ay += w0 * __uint_as_float(p0 & 0xffff0000u);
    }
    float di = dinv[node];
    ax = fmaxf(di * ax + b[lane * 2 + 0], 0.0f);
    ay = fmaxf(di * ay + b[lane * 2 + 1], 0.0f);
    uint o = ((uint)f2bf(ay) << 16) | (uint)f2bf(ax);
    *(uint*)&outp[(size_t)node * 128 + lane * 2] = o;
}

// ---- pool stage 1: wave per node; agg3[d] = dinv_d*(sum ew*z'[s] + z'[d]); pool by graph ----
__global__ __launch_bounds__(256) void k_pool_node(const int* __restrict__ cnt,
                                                   const uint* __restrict__ ell,
                                                   const float* __restrict__ dinv,
                                                   const float* __restrict__ z,
                                                   const int* __restrict__ batch,
                                                   float* __restrict__ partial) {
    __shared__ float ls[NG * CO + NG];
    for (int i = threadIdx.x; i < NG * CO + NG; i += 256) ls[i] = 0.0f;
    __syncthreads();
    int lane = threadIdx.x & 63;
    int gwave = blockIdx.x * 4 + (threadIdx.x >> 6);
    for (int node = gwave; node < NN; node += NB * 4) {
        int n = cnt[node];
        float w = 0.0f; int s = 0;
        if (lane < n) {
            uint rec = ell[(size_t)node * CAP + lane];
            s = (int)(rec & 0xffffu);
            w = (float)(rec >> 16) * EWS;
        } else if (lane == n) {
            s = node;
            w = 1.0f;                 // self term: z'[d]
        }
        const float* zp = &z[(size_t)s * 10];
        float v[10];
#pragma unroll
        for (int f = 0; f < 10; f++) v[f] = w * zp[f];
#pragma unroll
        for (int off = 32; off; off >>= 1) {
#pragma unroll
            for (int f = 0; f < 10; f++) v[f] += __shfl_down(v[f], off);
        }
        if (lane == 0) {
            int g = batch[node];
            float di = dinv[node];
            float* lp = &ls[g * 10];
#pragma unroll
            for (int f = 0; f < 10; f++) atomicAdd(&lp[f], di * v[f]);
            atomicAdd(&ls[NG * CO + g], 1.0f);
        }
    }
    __syncthreads();
    float* pb = &partial[(size_t)blockIdx.x * (NG * CO + NG)];
    for (int i = threadIdx.x; i < NG * CO + NG; i += 256) pb[i] = ls[i];
}

// ---- pool stage 2 + log_softmax: one block (256 thr) per graph ----
__global__ __launch_bounds__(256) void k_pool_final(const float* __restrict__ partial,
                                                    const float* __restrict__ b3,
                                                    float* __restrict__ out) {
    __shared__ float red[4][11];
    int g = blockIdx.x;
    int t = threadIdx.x;
    int lane = t & 63, wv = t >> 6;
    float v[10]; float c = 0.0f;
#pragma unroll
    for (int f = 0; f < 10; f++) v[f] = 0.0f;
    for (int b = t; b < NB; b += 256) {
        const float* pb = &partial[(size_t)b * (NG * CO + NG)];
#pragma unroll
        for (int f = 0; f < 10; f++) v[f] += pb[g * 10 + f];
        c += pb[NG * CO + g];
    }
#pragma unroll
    for (int off = 32; off; off >>= 1) {
#pragma unroll
        for (int f = 0; f < 10; f++) v[f] += __shfl_down(v[f], off);
        c += __shfl_down(c, off);
    }
    if (lane == 0) {
#pragma unroll
        for (int f = 0; f < 10; f++) red[wv][f] = v[f];
        red[wv][10] = c;
    }
    __syncthreads();
    if (t == 0) {
        float p[10], m = -1e30f;
        float cc = red[0][10] + red[1][10] + red[2][10] + red[3][10];
        cc = fmaxf(cc, 1.0f);
#pragma unroll
        for (int f = 0; f < 10; f++) {
            p[f] = (red[0][f] + red[1][f] + red[2][f] + red[3][f]) / cc + b3[f];
            m = fmaxf(m, p[f]);
        }
        float ssum = 0.0f;
#pragma unroll
        for (int f = 0; f < 10; f++) ssum += __expf(p[f] - m);
        float lse = m + __logf(ssum);
#pragma unroll
        for (int f = 0; f < 10; f++) out[g * 10 + f] = p[f] - lse;
    }
}

extern "C" void kernel_launch(void* const* d_in, const int* in_sizes, int n_in,
                              void* d_out, int out_size, void* d_ws, size_t ws_size,
                              hipStream_t stream) {
    const float* x     = (const float*)d_in[0];
    const int*   ei    = (const int*)d_in[1];     // [2, E]
    const float* ea    = (const float*)d_in[2];
    const int*   batch = (const int*)d_in[3];
    const float* W1    = (const float*)d_in[4];
    const float* b1    = (const float*)d_in[5];
    const float* W2    = (const float*)d_in[6];
    const float* b2    = (const float*)d_in[7];
    const float* W3    = (const float*)d_in[8];
    const float* b3    = (const float*)d_in[9];
    float* out = (float*)d_out;
    float* ws  = (float*)d_ws;

    const int* esrc = ei;
    const int* edst = ei + NE;

    // workspace layout (float offsets; all even -> 16B aligned)
    ushort* hb      = (ushort*)ws;                 // N*128 bf16 = 3,200,000 floats
    ushort* gb      = (ushort*)(ws + 3200000);     // N*128 bf16 = 3,200,000 floats
    float*  z       = ws + 6400000;                // 500,000
    float*  dinv    = ws + 6900000;                // 50,000
    int*    cnt     = (int*)(ws + 6950000);        // 50,000 ints
    uint*   ell     = (uint*)(ws + 7000000);       // NN*CAP u32 = 3,200,000
    ushort* wt1     = (ushort*)(ws + 10200000);    // 16384 ushorts (bf16 W1^T)
    ushort* wt2     = (ushort*)(ws + 10210000);    // 16384 ushorts (bf16 W2^T)
    float*  partial = (float*)hb;                  // NB*1408 floats, overlays hb
                                                   // (hb dead after gather-2)

    // --- ELL build + normalization + weight prep ---
    hipMemsetAsync(cnt, 0, NN * sizeof(int), stream);
    k_ell<<<(NE + 255) / 256, 256, 0, stream>>>(esrc, edst, ea, cnt, ell);
    k_prepw<<<64, 256, 0, stream>>>(W1, wt1);
    k_prepw<<<64, 256, 0, stream>>>(W2, wt2);
    k_deg<<<(NN + 3) / 4, 256, 0, stream>>>(cnt, ell, dinv);

    // --- layer 1: h' = dinv*(X@W1) (MFMA) ; gather -> gb (bf16) ---
    k_gemm_mfma<<<(NN + 63) / 64, 256, 0, stream>>>(x, 0, wt1, dinv, hb, NN);
    k_gather128<<<(NN + 3) / 4, 256, 0, stream>>>(cnt, ell, dinv, hb, b1, gb);

    // --- layer 2 ---
    k_gemm_mfma<<<(NN + 63) / 64, 256, 0, stream>>>(gb, 1, wt2, dinv, hb, NN);
    k_gather128<<<(NN + 3) / 4, 256, 0, stream>>>(cnt, ell, dinv, hb, b2, gb);

    // --- layer 3: z' = dinv*(gb@W3), pool over nodes ---
    k_gemm10<<<(NN + 15) / 16, 256, 0, stream>>>(gb, W3, dinv, z, NN);
    k_pool_node<<<NB, 256, 0, stream>>>(cnt, ell, dinv, z, batch, partial);
    k_pool_final<<<NG, 256, 0, stream>>>(partial, b3, out);
}